// Round 7
// baseline (434.260 us; speedup 1.0000x reference)
//
#include <hip/hip_runtime.h>
#include <math.h>

#define TOKENS   8192
#define HIDDEN   7168
#define NEXPERT  256
#define NGROUP   8
#define TOPKG    4
#define TOPK     8
#define SCALE    2.5f

// R13: R8 geometry + B-direct-from-image with FULL ping-pong prefetch.
// Constraint map from R8..R12 (gemm us: R8=137 best, R10=152, R12=174,
// R9=173, R11=300): need (a) dbuf staging overlapping MFMA, (b) >=2
// independent blocks/CU, (c) register-destined loads w/ counted vmcnt,
// (d) independent MFMA chains, (e) BOTH operands >=1 tile prefetch depth.
// R12 failed (e) for B (issued + consumed same tile, ~200cy cover vs
// ~200-225cy L2 latency). This round: R8's exact proven geometry
// (BM=BN=128, KSPLIT=4, 256 thr, 2x2 waves, 1 barrier/tile, dbuf A LDS)
// with the B path register-resident: finished B fragments from the
// pre-split W image (R11/R12-proven numerics), ping-pong B(t+1) issued
// after tile t's ds_reads -> consumed tile t+1 (cover = MFMA+stage+
// barrier+dsreads ~500cy >> L2 lat). Deletes per tile: 8 B ds_writes +
// 8 B ds_reads; LDS 72->36 KB. Cost: +64 VGPR ping-pong, 2 blk/CU.
#define BM 128
#define BN 128
#define BK 32
#define KSPLIT 4
#define KPB (HIDDEN / KSPLIT)   // 1792
#define NT  (KPB / BK)          // 56
#define WTILE_BYTES 32768       // W image tile (kz,t): 256 cols x 4 oct x 32 B

// A LDS layout (halves): addr(row,k,hl) = row*72 + (k>>3)*16 + hl*8 + (k&7).
// Row stride 144 B (R8-proven <=2-way bank aliasing on b128 frag reads).
// 128 x 72 x 2 B = 18 KB per buffer, dbuf 36 KB.
#define RSTR 72

typedef _Float16 half8 __attribute__((ext_vector_type(8)));
typedef _Float16 half4 __attribute__((ext_vector_type(4)));
typedef float    floatx4 __attribute__((ext_vector_type(4)));

// fp32 -> fp16 hi/lo split, store h4 at octet +0..7, l4 at +8..15
__device__ __forceinline__ void cvt_store(_Float16* __restrict__ H,
                                          int row, int k0, float4 v) {
    half4 h, l;
    h[0] = (_Float16)v.x; h[1] = (_Float16)v.y;
    h[2] = (_Float16)v.z; h[3] = (_Float16)v.w;
    l[0] = (_Float16)(v.x - (float)h[0]);
    l[1] = (_Float16)(v.y - (float)h[1]);
    l[2] = (_Float16)(v.z - (float)h[2]);
    l[3] = (_Float16)(v.w - (float)h[3]);
    const int base = row * RSTR + ((k0 >> 3) << 4) + (k0 & 7);
    *(half4*)&H[base]     = h;
    *(half4*)&H[base + 8] = l;
}

// fp32x8 -> fp16 hi/lo split (same RNE bits; used by wsplit).
// logit = sum al*bh + ah*bl + ah*bh in fp32 MFMA acc; dropped al*bl ~ 2^-22.
__device__ __forceinline__ void cvt8(const float4 a, const float4 b,
                                     half8& h, half8& l) {
    h[0] = (_Float16)a.x; h[1] = (_Float16)a.y;
    h[2] = (_Float16)a.z; h[3] = (_Float16)a.w;
    h[4] = (_Float16)b.x; h[5] = (_Float16)b.y;
    h[6] = (_Float16)b.z; h[7] = (_Float16)b.w;
    l[0] = (_Float16)(a.x - (float)h[0]); l[1] = (_Float16)(a.y - (float)h[1]);
    l[2] = (_Float16)(a.z - (float)h[2]); l[3] = (_Float16)(a.w - (float)h[3]);
    l[4] = (_Float16)(b.x - (float)h[4]); l[5] = (_Float16)(b.y - (float)h[5]);
    l[6] = (_Float16)(b.z - (float)h[6]); l[7] = (_Float16)(b.w - (float)h[7]);
}

// ---------------------------------------------------------------------------
// W pre-split + OUT zeroing fused. Image tile (kz,t): 256 cols x 4 k-octets
// x (hi8|lo8) = 32 KB; entry ((col*4+oct)*32) is the EXACT B-fragment pair
// the GEMM loads (16 B hi, 16 B lo). One block/expert, 896 threads.
// ---------------------------------------------------------------------------
__global__ __launch_bounds__(896) void wsplit_kernel(
    const float* __restrict__ W, char* __restrict__ WS, float* __restrict__ O)
{
    const int gt = blockIdx.x * 896 + threadIdx.x;
#pragma unroll
    for (int i = 0; i < 3; i++) {
        const int idx = gt + i * (NEXPERT * 896);
        if (idx < TOKENS * NEXPERT / 4)
            *(float4*)&O[(size_t)idx * 4] = float4{0.f, 0.f, 0.f, 0.f};
    }

    const int e  = blockIdx.x;          // expert 0..255
    const int og = threadIdx.x;         // k-octet within expert, 0..895
    const float4 a = *(const float4*)&W[(size_t)e * HIDDEN + og * 8];
    const float4 b = *(const float4*)&W[(size_t)e * HIDDEN + og * 8 + 4];
    half8 h, l;
    cvt8(a, b, h, l);

    const int kz = og / (KPB / 8);          // k-split 0..3 (224 octets per kz)
    const int tt = (og % (KPB / 8)) >> 2;   // k-tile  0..55
    const int oc = og & 3;                  // octet   0..3
    char* p = WS + (size_t)(kz * NT + tt) * WTILE_BYTES + (e * 4 + oc) * 32;
    *(half8*)p        = h;
    *(half8*)(p + 16) = l;
}

// ---------------------------------------------------------------------------
// Gate GEMM. Fragment maps (16x16x32_f16, R8-proven): A/B lane (fr,quad)
// holds row/col = base + fr, k = quad*8..+7. D: row = quad*4+reg, col = fr.
// Per tile: stage A(t) (vmcnt(8): waits A only, B(t) flies) -> issue A(t+1)
// -> barrier -> 8 A-frag ds_reads -> issue B(t+1) -> 48 MFMA on B(t)
// (vmcnt(12): A(t+1)+B(t+1) stay in flight; B(t) landed a full tile ago).
// ---------------------------------------------------------------------------
__global__ __launch_bounds__(256, 2) void gate_gemm_kernel(
    const float* __restrict__ X, const char* __restrict__ WS,
    float* __restrict__ OUT)
{
    __shared__ _Float16 Ab[2][BM * RSTR];   // 2 x 18 KB = 36 KB

    const int tid = threadIdx.x;
    const int nb  = blockIdx.x * BN;
    const int mb  = blockIdx.y * BM;
    const int kb  = blockIdx.z * KPB;

    // A staging map (R8): thread t takes rows q*32 + (t>>3), k0 = (t&7)*4
    const int srow = tid >> 3;            // 0..31 (+q*32)
    const int sk0  = (tid & 7) * 4;       // 0..28
    const float* Aptr = X + (size_t)(mb + srow) * HIDDEN + kb + sk0;

    const int lane = tid & 63, wave = tid >> 6;
    const int wm = (wave >> 1) * 64, wn = (wave & 1) * 64;
    const int fr = lane & 15, quad = lane >> 4;

    // B: lane loads image (kz,t) at col = nb + wn + j*16 + fr, oct = quad;
    // 16 B hi at +0, 16 B lo at +16 — finished MFMA fragments.
    const char* Bbase = WS + (size_t)(blockIdx.z * NT) * WTILE_BYTES
                      + (nb + wn + fr) * 128 + quad * 32;

    // prologue: issue A(0) first, then B(0) -> stage's A-wait is vmcnt(8)
    float4 av[4];
#pragma unroll
    for (int q = 0; q < 4; q++)
        av[q] = *(const float4*)(Aptr + (size_t)(q * 32) * HIDDEN);
    half8 bhA[4], blA[4], bhB[4], blB[4];   // ping-pong (static idx, rule #20)
#pragma unroll
    for (int j = 0; j < 4; j++) {
        bhA[j] = *(const half8*)(Bbase + j * 2048);
        blA[j] = *(const half8*)(Bbase + j * 2048 + 16);
    }

    floatx4 acc[4][4];
#pragma unroll
    for (int i = 0; i < 4; i++)
#pragma unroll
        for (int j = 0; j < 4; j++) acc[i][j] = floatx4{0.f, 0.f, 0.f, 0.f};

    // STEP(T): stage A(T) from av (waits A(T) only); issue A(T+1); barrier;
    // A-frag ds_reads; issue B(T+1) into BHN/BLN; 48 MFMA on BHC/BLC = B(T).
#define STEP(T, BHC, BLC, BHN, BLN)                                           \
    {                                                                         \
        _Pragma("unroll")                                                     \
        for (int q = 0; q < 4; q++)                                           \
            cvt_store(Ab[(T) & 1], q * 32 + srow, sk0, av[q]);                \
        const int tn = ((T) + 1 < NT) ? (T) + 1 : NT - 1;                     \
        _Pragma("unroll")                                                     \
        for (int q = 0; q < 4; q++)                                           \
            av[q] = *(const float4*)(Aptr + tn * BK                           \
                                     + (size_t)(q * 32) * HIDDEN);            \
        __syncthreads();                                                      \
        const _Float16* Ac = Ab[(T) & 1];                                     \
        half8 ah[4], al[4];                                                   \
        _Pragma("unroll")                                                     \
        for (int i = 0; i < 4; i++) {                                         \
            const int a = (wm + i * 16 + fr) * RSTR + quad * 16;              \
            ah[i] = *(const half8*)&Ac[a];                                    \
            al[i] = *(const half8*)&Ac[a + 8];                                \
        }                                                                     \
        const char* bp = Bbase + (size_t)tn * WTILE_BYTES;                    \
        _Pragma("unroll")                                                     \
        for (int j = 0; j < 4; j++) {                                         \
            BHN[j] = *(const half8*)(bp + j * 2048);                          \
            BLN[j] = *(const half8*)(bp + j * 2048 + 16);                     \
        }                                                                     \
        _Pragma("unroll")                                                     \
        for (int j = 0; j < 4; j++)                                           \
            _Pragma("unroll")                                                 \
            for (int i = 0; i < 4; i++) {                                     \
                acc[i][j] = __builtin_amdgcn_mfma_f32_16x16x32_f16(           \
                    al[i], BHC[j], acc[i][j], 0, 0, 0);                       \
                acc[i][j] = __builtin_amdgcn_mfma_f32_16x16x32_f16(           \
                    ah[i], BLC[j], acc[i][j], 0, 0, 0);                       \
                acc[i][j] = __builtin_amdgcn_mfma_f32_16x16x32_f16(           \
                    ah[i], BHC[j], acc[i][j], 0, 0, 0);                       \
            }                                                                 \
    }

    for (int t = 0; t < NT; t += 2) {       // NT = 56, even
        STEP(t,     bhA, blA, bhB, blB)
        STEP(t + 1, bhB, blB, bhA, blA)
    }
#undef STEP

    // epilogue: D row = token (quad*4+reg), col = expert (fr);
    // split-K accumulation via atomicAdd (R3/R8-proven, 4-way)
#pragma unroll
    for (int i = 0; i < 4; i++)
#pragma unroll
        for (int j = 0; j < 4; j++) {
            const int col = nb + wn + j * 16 + fr;
#pragma unroll
            for (int r = 0; r < 4; r++) {
                const int row = mb + wm + i * 16 + quad * 4 + r;
                atomicAdd(&OUT[(size_t)row * NEXPERT + col], acc[i][j][r]);
            }
        }
}

// ---------------------------------------------------------------------------
// Routing: one wave per token, in-place on d_out (logits -> gate weights).
// Sigmoid fused; exact jax semantics incl. lowest-index tie-breaks.
// ---------------------------------------------------------------------------
__global__ __launch_bounds__(256) void route_kernel(
    float* __restrict__ S, const float* __restrict__ bias)
{
    const int lane = threadIdx.x & 63;
    const int wave = threadIdx.x >> 6;
    const int t    = blockIdx.x * 4 + wave;

    const float4 lg4 = *(const float4*)&S[(size_t)t * NEXPERT + lane * 4];
    const float4 b4  = *(const float4*)&bias[lane * 4];
    float sc[4];
    sc[0] = 1.0f / (1.0f + expf(-lg4.x));
    sc[1] = 1.0f / (1.0f + expf(-lg4.y));
    sc[2] = 1.0f / (1.0f + expf(-lg4.z));
    sc[3] = 1.0f / (1.0f + expf(-lg4.w));
    float swb[4] = { sc[0] + b4.x, sc[1] + b4.y, sc[2] + b4.z, sc[3] + b4.w };

    // per-lane top-2 of 4
    float m1 = -INFINITY, m2 = -INFINITY;
#pragma unroll
    for (int j = 0; j < 4; j++) {
        const float v = swb[j];
        if (v > m1)      { m2 = m1; m1 = v; }
        else if (v > m2) { m2 = v; }
    }
    // merge across the 8 lanes of my group
#pragma unroll
    for (int s = 1; s < 8; s <<= 1) {
        const float o1 = __shfl_xor(m1, s, 64);
        const float o2 = __shfl_xor(m2, s, 64);
        const float hi = fmaxf(m1, o1);
        const float lo = fminf(m1, o1);
        m2 = fmaxf(lo, fmaxf(m2, o2));
        m1 = hi;
    }
    const float gs = m1 + m2;

    // top-4 groups by rank (tie -> lower group index)
    float gsc[NGROUP];
#pragma unroll
    for (int g = 0; g < NGROUP; g++) gsc[g] = __shfl(gs, g * 8, 64);
    const int myg = lane >> 3;
    int rank = 0;
#pragma unroll
    for (int g = 0; g < NGROUP; g++)
        rank += (gsc[g] > gs) || (gsc[g] == gs && g < myg);
    const bool kept = (rank < TOPKG);

    float v[4];
#pragma unroll
    for (int j = 0; j < 4; j++) v[j] = kept ? swb[j] : 0.0f;

    // top-8 experts: 8 rounds of wave argmax (lowest idx on ties)
    float sum = 0.0f;
    int selmask = 0;
    for (int r = 0; r < TOPK; r++) {
        float bv = -INFINITY;
        int   bi = 0x7fffffff;
#pragma unroll
        for (int j = 0; j < 4; j++) {
            const bool avail = ((selmask >> j) & 1) == 0;
            if (avail && v[j] > bv) { bv = v[j]; bi = lane * 4 + j; }
        }
#pragma unroll
        for (int s = 1; s < 64; s <<= 1) {
            const float ov = __shfl_xor(bv, s, 64);
            const int   oi = __shfl_xor(bi, s, 64);
            if (ov > bv || (ov == bv && oi < bi)) { bv = ov; bi = oi; }
        }
        const int wl = bi >> 2, wj = bi & 3;
        const float mysc = (wj == 0) ? sc[0] : (wj == 1) ? sc[1]
                         : (wj == 2) ? sc[2] : sc[3];
        sum += __shfl(mysc, wl, 64);
        if (lane == wl) selmask |= (1 << wj);
    }

    const float rcp = SCALE / (sum + 1e-20f);
    float4 o;
    o.x = (selmask & 1) ? sc[0] * rcp : 0.0f;
    o.y = (selmask & 2) ? sc[1] * rcp : 0.0f;
    o.z = (selmask & 4) ? sc[2] * rcp : 0.0f;
    o.w = (selmask & 8) ? sc[3] * rcp : 0.0f;
    *(float4*)&S[(size_t)t * NEXPERT + lane * 4] = o;
}

extern "C" void kernel_launch(void* const* d_in, const int* in_sizes, int n_in,
                              void* d_out, int out_size, void* d_ws, size_t ws_size,
                              hipStream_t stream) {
    const float* X    = (const float*)d_in[0];   // [8192, 7168]
    const float* W    = (const float*)d_in[1];   // [256, 7168]
    const float* bias = (const float*)d_in[2];   // [256]
    float* out = (float*)d_out;                  // [8192, 256]
    // d_ws: 4*56 tiles x 32 KB = 7,340,032 B of pre-split W-fragment images.
    // Harness poison-fills d_ws every iteration regardless of use (R0-R2
    // evidence) -> using it is free; we rewrite our slice before the GEMM.
    char* ws = (char*)d_ws; (void)ws_size;

    wsplit_kernel<<<NEXPERT, 896, 0, stream>>>(W, ws, out);
    dim3 ggrid(NEXPERT / BN, TOKENS / BM, KSPLIT);  // (2, 64, 4) = 512 blocks
    gate_gemm_kernel<<<ggrid, 256, 0, stream>>>(X, ws, out);
    route_kernel<<<TOKENS / 4, 256, 0, stream>>>(out, bias);
}

// Round 12
// 385.803 us; speedup vs baseline: 1.1256x; 1.1256x over previous
//
#include <hip/hip_runtime.h>
#include <math.h>

#define TOKENS   8192
#define HIDDEN   7168
#define NEXPERT  256
#define NGROUP   8
#define TOPKG    4
#define TOPK     8
#define SCALE    2.5f

// R14 (4th resubmit; R8/R9/R10/R11 benches all failed on infrastructure —
// GPUAcquisitionTimeout x3, container-failure x1. Kernel never measured.)
// R8's proven structure (best measured gemm, 137 us) with ONE change:
// the stage phase is folded INSIDE the MFMA cluster.
// Cross-round facts driving this:
//  - non-gemm residual is constant 244-252 us across R0-R13 -> only the
//    gemm is a lever.
//  - R8's 137 ~= LDS(54) + MFMA(43.5) + HBM-wait(39): the three pipes run
//    SERIALLY. Variants that changed topology (R9-R13) all broke one of the
//    proven constraints and regressed; the fix is in-wave overlap.
//  - R13's VGPR_Count=84 proved the compiler DEMOTES fat register prefetch;
//    LDS dbuf staging (R8) is the schedule the compiler preserves.
// Per tile now: dsreads(t) -> MFMA j=0,1 -> stage(t+1)+issue loads(t+2)
//   -> sched_barrier(0) -> MFMA j=2,3 -> __syncthreads().
//  - A(t+1) vmcnt wait sits after ~300cy of frag-reads+MFMA half1 (R8 had
//    it in a dead spot right after the barrier).
//  - DS writes execute while the wave issues MFMA half2 (stores don't
//    block): LDS-write traffic overlaps the matrix pipe IN-WAVE.
//  - setprio(1) around MFMA halves (T5: 2 blocks/CU give phase diversity).
// Accumulation order per acc[i][j] identical to R8 -> bit-exact, absmax 0.
#define BM 128
#define BN 128
#define BK 32
#define KSPLIT 4
#define KPB (HIDDEN / KSPLIT)   // 1792
#define NT  (KPB / BK)          // 56
#define TILE_BYTES 16384        // W image tile: 128 rows x 4 octets x 32 B

// LDS layout (halves): addr(row,k,hl) = row*72 + (k>>3)*16 + hl*8 + (k&7).
// Row stride 144 B (R8-proven <=2-way bank aliasing on b128 frag reads).
#define RSTR 72

typedef _Float16 half8 __attribute__((ext_vector_type(8)));
typedef _Float16 half4 __attribute__((ext_vector_type(4)));
typedef float    floatx4 __attribute__((ext_vector_type(4)));

// fp32 -> fp16 hi/lo split, store h4 at octet +0..7, l4 at +8..15
__device__ __forceinline__ void cvt_store(_Float16* __restrict__ H,
                                          int row, int k0, float4 v) {
    half4 h, l;
    h[0] = (_Float16)v.x; h[1] = (_Float16)v.y;
    h[2] = (_Float16)v.z; h[3] = (_Float16)v.w;
    l[0] = (_Float16)(v.x - (float)h[0]);
    l[1] = (_Float16)(v.y - (float)h[1]);
    l[2] = (_Float16)(v.z - (float)h[2]);
    l[3] = (_Float16)(v.w - (float)h[3]);
    const int base = row * RSTR + ((k0 >> 3) << 4) + (k0 & 7);
    *(half4*)&H[base]     = h;
    *(half4*)&H[base + 8] = l;
}

// fp32x8 -> fp16 hi/lo split (same RNE bits; used by wsplit).
// logit = sum al*bh + ah*bl + ah*bh in fp32 MFMA acc; dropped al*bl ~ 2^-22.
__device__ __forceinline__ void cvt8(const float4 a, const float4 b,
                                     half8& h, half8& l) {
    h[0] = (_Float16)a.x; h[1] = (_Float16)a.y;
    h[2] = (_Float16)a.z; h[3] = (_Float16)a.w;
    h[4] = (_Float16)b.x; h[5] = (_Float16)b.y;
    h[6] = (_Float16)b.z; h[7] = (_Float16)b.w;
    l[0] = (_Float16)(a.x - (float)h[0]); l[1] = (_Float16)(a.y - (float)h[1]);
    l[2] = (_Float16)(a.z - (float)h[2]); l[3] = (_Float16)(a.w - (float)h[3]);
    l[4] = (_Float16)(b.x - (float)h[4]); l[5] = (_Float16)(b.y - (float)h[5]);
    l[6] = (_Float16)(b.z - (float)h[6]); l[7] = (_Float16)(b.w - (float)h[7]);
}

// ---------------------------------------------------------------------------
// W pre-split + OUT zeroing fused. Tile (nb,kz,t): 128 rows x 4 octets x
// (hi8|lo8) = 16 KB, octet-contiguous = GEMM B-staging reads (R8 layout).
// One block/expert, 896 threads, one k-octet each.
// ---------------------------------------------------------------------------
__global__ __launch_bounds__(896) void wsplit_kernel(
    const float* __restrict__ W, char* __restrict__ WS, float* __restrict__ O)
{
    const int gt = blockIdx.x * 896 + threadIdx.x;
#pragma unroll
    for (int i = 0; i < 3; i++) {
        const int idx = gt + i * (NEXPERT * 896);
        if (idx < TOKENS * NEXPERT / 4)
            *(float4*)&O[(size_t)idx * 4] = float4{0.f, 0.f, 0.f, 0.f};
    }

    const int e  = blockIdx.x;          // expert 0..255
    const int og = threadIdx.x;         // k-octet within expert, 0..895
    const float4 a = *(const float4*)&W[(size_t)e * HIDDEN + og * 8];
    const float4 b = *(const float4*)&W[(size_t)e * HIDDEN + og * 8 + 4];
    half8 h, l;
    cvt8(a, b, h, l);

    const int kz = og / (KPB / 8);          // k-split 0..3 (224 octets per kz)
    const int tt = (og % (KPB / 8)) >> 2;   // k-tile  0..55
    const int oc = og & 3;                  // octet   0..3
    const int row = e & 127, nb = e >> 7;
    char* p = WS + (size_t)((nb * KSPLIT + kz) * NT + tt) * TILE_BYTES
            + (row * 4 + oc) * 32;
    *(half8*)p        = h;
    *(half8*)(p + 16) = l;
}

// ---------------------------------------------------------------------------
// Gate GEMM. Fragment maps (16x16x32_f16, R8-proven): A/B lane (fr,quad)
// holds row/col = base + fr, k = quad*8..+7. D: row = quad*4+reg, col = fr.
// ---------------------------------------------------------------------------
__global__ __launch_bounds__(256, 2) void gate_gemm_kernel(
    const float* __restrict__ X, const char* __restrict__ WS,
    float* __restrict__ OUT)
{
    __shared__ _Float16 Ab[2][BM * RSTR];   // 2 x 18 KB
    __shared__ _Float16 Bb[2][BN * RSTR];   // 2 x 18 KB  -> 72 KB total

    const int tid = threadIdx.x;
    const int nb  = blockIdx.x * BN;
    const int mb  = blockIdx.y * BM;
    const int kb  = blockIdx.z * KPB;

    // A staging map (R8): thread t takes rows q*32 + (t>>3), k0 = (t&7)*4
    const int srow = tid >> 3;            // 0..31 (+q*32)
    const int sk0  = (tid & 7) * 4;       // 0..28
    const float* Aptr = X + (size_t)(mb + srow) * HIDDEN + kb + sk0;

    // B staging map (R8): pair p = tid + 256*s -> row = p>>2, oct = p&3;
    // 32 B contiguous (hi8|lo8) per pair in the packed W image.
    const char* Wimg =
        WS + (size_t)((blockIdx.x * KSPLIT + blockIdx.z) * NT) * TILE_BYTES;
    const int bbase[2] = { (tid >> 2) * RSTR + (tid & 3) * 16,
                           ((tid >> 2) + 64) * RSTR + (tid & 3) * 16 };

    const int lane = tid & 63, wave = tid >> 6;
    const int wm = (wave >> 1) * 64, wn = (wave & 1) * 64;
    const int fr = lane & 15, quad = lane >> 4;

    // prologue: load tile 0, stage it, issue tile 1 into the other bank
    float4 avA[4], avB[4];
    half8  nhA[2], nlA[2], nhB[2], nlB[2];
#pragma unroll
    for (int q = 0; q < 4; q++)
        avA[q] = *(const float4*)(Aptr + (size_t)(q * 32) * HIDDEN);
#pragma unroll
    for (int s = 0; s < 2; s++) {
        const char* src = Wimg + (tid + 256 * s) * 32;
        nhA[s] = *(const half8*)src;
        nlA[s] = *(const half8*)(src + 16);
    }
#pragma unroll
    for (int q = 0; q < 4; q++)
        cvt_store(Ab[0], q * 32 + srow, sk0, avA[q]);
#pragma unroll
    for (int s = 0; s < 2; s++) {
        *(half8*)&Bb[0][bbase[s]]     = nhA[s];
        *(half8*)&Bb[0][bbase[s] + 8] = nlA[s];
    }
    // issue tile 1 into bank B
#pragma unroll
    for (int q = 0; q < 4; q++)
        avB[q] = *(const float4*)(Aptr + BK + (size_t)(q * 32) * HIDDEN);
    {
        const char* srcT = Wimg + (size_t)1 * TILE_BYTES;
#pragma unroll
        for (int s = 0; s < 2; s++) {
            const char* src = srcT + (tid + 256 * s) * 32;
            nhB[s] = *(const half8*)src;
            nlB[s] = *(const half8*)(src + 16);
        }
    }
    __syncthreads();

    floatx4 acc[4][4];
#pragma unroll
    for (int i = 0; i < 4; i++)
#pragma unroll
        for (int j = 0; j < 4; j++) acc[i][j] = floatx4{0.f, 0.f, 0.f, 0.f};

    // STEP(T): consume buf[T&1]; MFMA half1; stage tile T+1 from bank C
    // (regs issued one iteration ago); issue tile T+2 into bank N;
    // MFMA half2; barrier. Accumulation order per acc == R8 (bit-exact).
#define STEP(T, AVC, NHC, NLC, AVN, NHN, NLN)                                 \
    {                                                                         \
        const _Float16* Ac = Ab[(T) & 1];                                     \
        const _Float16* Bc = Bb[(T) & 1];                                     \
        half8 ah[4], al[4], bh[4], bl[4];                                     \
        _Pragma("unroll")                                                     \
        for (int i = 0; i < 4; i++) {                                         \
            const int a = (wm + i * 16 + fr) * RSTR + quad * 16;              \
            ah[i] = *(const half8*)&Ac[a];                                    \
            al[i] = *(const half8*)&Ac[a + 8];                                \
        }                                                                     \
        _Pragma("unroll")                                                     \
        for (int j = 0; j < 4; j++) {                                         \
            const int b = (wn + j * 16 + fr) * RSTR + quad * 16;              \
            bh[j] = *(const half8*)&Bc[b];                                    \
            bl[j] = *(const half8*)&Bc[b + 8];                                \
        }                                                                     \
        __builtin_amdgcn_s_setprio(1);                                       \
        _Pragma("unroll")                                                     \
        for (int j = 0; j < 2; j++)                                           \
            _Pragma("unroll")                                                 \
            for (int i = 0; i < 4; i++) {                                     \
                acc[i][j] = __builtin_amdgcn_mfma_f32_16x16x32_f16(           \
                    al[i], bh[j], acc[i][j], 0, 0, 0);                        \
                acc[i][j] = __builtin_amdgcn_mfma_f32_16x16x32_f16(           \
                    ah[i], bl[j], acc[i][j], 0, 0, 0);                        \
                acc[i][j] = __builtin_amdgcn_mfma_f32_16x16x32_f16(           \
                    ah[i], bh[j], acc[i][j], 0, 0, 0);                        \
            }                                                                 \
        __builtin_amdgcn_s_setprio(0);                                       \
        if ((T) + 1 < NT) {                                                   \
            _Float16* An = Ab[((T) + 1) & 1];                                 \
            _Float16* Bn = Bb[((T) + 1) & 1];                                 \
            _Pragma("unroll")                                                 \
            for (int q = 0; q < 4; q++)                                       \
                cvt_store(An, q * 32 + srow, sk0, AVC[q]);                    \
            _Pragma("unroll")                                                 \
            for (int s = 0; s < 2; s++) {                                     \
                *(half8*)&Bn[bbase[s]]     = NHC[s];                          \
                *(half8*)&Bn[bbase[s] + 8] = NLC[s];                          \
            }                                                                 \
            const int tn = ((T) + 2 < NT) ? (T) + 2 : NT - 1;                 \
            _Pragma("unroll")                                                 \
            for (int q = 0; q < 4; q++)                                       \
                AVN[q] = *(const float4*)(Aptr + tn * BK                      \
                                          + (size_t)(q * 32) * HIDDEN);       \
            const char* srcT = Wimg + (size_t)tn * TILE_BYTES;                \
            _Pragma("unroll")                                                 \
            for (int s = 0; s < 2; s++) {                                     \
                const char* src = srcT + (tid + 256 * s) * 32;                \
                NHN[s] = *(const half8*)src;                                  \
                NLN[s] = *(const half8*)(src + 16);                           \
            }                                                                 \
        }                                                                     \
        __builtin_amdgcn_sched_barrier(0);  /* pin stores before half2 */     \
        __builtin_amdgcn_s_setprio(1);                                       \
        _Pragma("unroll")                                                     \
        for (int j = 2; j < 4; j++)                                           \
            _Pragma("unroll")                                                 \
            for (int i = 0; i < 4; i++) {                                     \
                acc[i][j] = __builtin_amdgcn_mfma_f32_16x16x32_f16(           \
                    al[i], bh[j], acc[i][j], 0, 0, 0);                        \
                acc[i][j] = __builtin_amdgcn_mfma_f32_16x16x32_f16(           \
                    ah[i], bl[j], acc[i][j], 0, 0, 0);                        \
                acc[i][j] = __builtin_amdgcn_mfma_f32_16x16x32_f16(           \
                    ah[i], bh[j], acc[i][j], 0, 0, 0);                        \
            }                                                                 \
        __builtin_amdgcn_s_setprio(0);                                       \
        __syncthreads();                                                      \
    }

    for (int t = 0; t < NT; t += 2) {       // NT = 56, even
        STEP(t,     avB, nhB, nlB, avA, nhA, nlA)
        STEP(t + 1, avA, nhA, nlA, avB, nhB, nlB)
    }
#undef STEP

    // epilogue: D row = token (quad*4+reg), col = expert (fr);
    // split-K accumulation via atomicAdd (R3/R8-proven, 4-way)
#pragma unroll
    for (int i = 0; i < 4; i++)
#pragma unroll
        for (int j = 0; j < 4; j++) {
            const int col = nb + wn + j * 16 + fr;
#pragma unroll
            for (int r = 0; r < 4; r++) {
                const int row = mb + wm + i * 16 + quad * 4 + r;
                atomicAdd(&OUT[(size_t)row * NEXPERT + col], acc[i][j][r]);
            }
        }
}

// ---------------------------------------------------------------------------
// Routing: one wave per token, in-place on d_out (logits -> gate weights).
// Sigmoid fused; exact jax semantics incl. lowest-index tie-breaks.
// ---------------------------------------------------------------------------
__global__ __launch_bounds__(256) void route_kernel(
    float* __restrict__ S, const float* __restrict__ bias)
{
    const int lane = threadIdx.x & 63;
    const int wave = threadIdx.x >> 6;
    const int t    = blockIdx.x * 4 + wave;

    const float4 lg4 = *(const float4*)&S[(size_t)t * NEXPERT + lane * 4];
    const float4 b4  = *(const float4*)&bias[lane * 4];
    float sc[4];
    sc[0] = 1.0f / (1.0f + expf(-lg4.x));
    sc[1] = 1.0f / (1.0f + expf(-lg4.y));
    sc[2] = 1.0f / (1.0f + expf(-lg4.z));
    sc[3] = 1.0f / (1.0f + expf(-lg4.w));
    float swb[4] = { sc[0] + b4.x, sc[1] + b4.y, sc[2] + b4.z, sc[3] + b4.w };

    // per-lane top-2 of 4
    float m1 = -INFINITY, m2 = -INFINITY;
#pragma unroll
    for (int j = 0; j < 4; j++) {
        const float v = swb[j];
        if (v > m1)      { m2 = m1; m1 = v; }
        else if (v > m2) { m2 = v; }
    }
    // merge across the 8 lanes of my group
#pragma unroll
    for (int s = 1; s < 8; s <<= 1) {
        const float o1 = __shfl_xor(m1, s, 64);
        const float o2 = __shfl_xor(m2, s, 64);
        const float hi = fmaxf(m1, o1);
        const float lo = fminf(m1, o1);
        m2 = fmaxf(lo, fmaxf(m2, o2));
        m1 = hi;
    }
    const float gs = m1 + m2;

    // top-4 groups by rank (tie -> lower group index)
    float gsc[NGROUP];
#pragma unroll
    for (int g = 0; g < NGROUP; g++) gsc[g] = __shfl(gs, g * 8, 64);
    const int myg = lane >> 3;
    int rank = 0;
#pragma unroll
    for (int g = 0; g < NGROUP; g++)
        rank += (gsc[g] > gs) || (gsc[g] == gs && g < myg);
    const bool kept = (rank < TOPKG);

    float v[4];
#pragma unroll
    for (int j = 0; j < 4; j++) v[j] = kept ? swb[j] : 0.0f;

    // top-8 experts: 8 rounds of wave argmax (lowest idx on ties)
    float sum = 0.0f;
    int selmask = 0;
    for (int r = 0; r < TOPK; r++) {
        float bv = -INFINITY;
        int   bi = 0x7fffffff;
#pragma unroll
        for (int j = 0; j < 4; j++) {
            const bool avail = ((selmask >> j) & 1) == 0;
            if (avail && v[j] > bv) { bv = v[j]; bi = lane * 4 + j; }
        }
#pragma unroll
        for (int s = 1; s < 64; s <<= 1) {
            const float ov = __shfl_xor(bv, s, 64);
            const int   oi = __shfl_xor(bi, s, 64);
            if (ov > bv || (ov == bv && oi < bi)) { bv = ov; bi = oi; }
        }
        const int wl = bi >> 2, wj = bi & 3;
        const float mysc = (wj == 0) ? sc[0] : (wj == 1) ? sc[1]
                         : (wj == 2) ? sc[2] : sc[3];
        sum += __shfl(mysc, wl, 64);
        if (lane == wl) selmask |= (1 << wj);
    }

    const float rcp = SCALE / (sum + 1e-20f);
    float4 o;
    o.x = (selmask & 1) ? sc[0] * rcp : 0.0f;
    o.y = (selmask & 2) ? sc[1] * rcp : 0.0f;
    o.z = (selmask & 4) ? sc[2] * rcp : 0.0f;
    o.w = (selmask & 8) ? sc[3] * rcp : 0.0f;
    *(float4*)&S[(size_t)t * NEXPERT + lane * 4] = o;
}

extern "C" void kernel_launch(void* const* d_in, const int* in_sizes, int n_in,
                              void* d_out, int out_size, void* d_ws, size_t ws_size,
                              hipStream_t stream) {
    const float* X    = (const float*)d_in[0];   // [8192, 7168]
    const float* W    = (const float*)d_in[1];   // [256, 7168]
    const float* bias = (const float*)d_in[2];   // [256]
    float* out = (float*)d_out;                  // [8192, 256]
    // d_ws: 2*4*56 tiles x 16 KB = 7,340,032 B of pre-split W images.
    // Harness poison-fills d_ws every iteration regardless of use (R0-R2
    // evidence) -> using it is free; we rewrite our slice before the GEMM.
    char* ws = (char*)d_ws; (void)ws_size;

    wsplit_kernel<<<NEXPERT, 896, 0, stream>>>(W, ws, out);
    dim3 ggrid(NEXPERT / BN, TOKENS / BM, KSPLIT);  // (2, 64, 4) = 512 blocks
    gate_gemm_kernel<<<ggrid, 256, 0, stream>>>(X, ws, out);
    route_kernel<<<TOKENS / 4, 256, 0, stream>>>(out, bias);
}